// Round 3
// baseline (1960.382 us; speedup 1.0000x reference)
//
#include <hip/hip_runtime.h>
#include <hip/hip_bf16.h>

// Problem constants (fixed by setup_inputs)
#define T_TOK 4096
#define DDIM  2048
#define FDIM  4096
#define NEXP  8
#define XTOP  2
#define ATOT  8192   // T_TOK * XTOP
#define MT_MAX 72    // max M-tiles of 128 rows: 8192/128 + (NEXP-1) padding < 72

// meta layout (int offsets) inside workspace
#define OFF_COUNTS 0       // [32][8] per-chunk expert counts -> chunk bases after scan
#define OFF_LRANK  256     // [ATOT]
#define OFF_ROWSRC 8448    // [ATOT] sorted pos -> assignment id
#define OFF_POSOF  16640   // [ATOT] assignment id -> sorted pos
#define OFF_ESTART 24832   // [9]
#define OFF_TROW0  24848   // [MT_MAX]
#define OFF_TREND  24928   // [MT_MAX]
#define OFF_TE     25008   // [MT_MAX]

typedef short bf16x8 __attribute__((ext_vector_type(8)));
typedef float f32x4  __attribute__((ext_vector_type(4)));

__device__ __forceinline__ unsigned short f2bf(float f) {
  union { __hip_bfloat16 b; unsigned short u; } v;
  v.b = __float2bfloat16(f);
  return v.u;
}
__device__ __forceinline__ unsigned pack2(float a, float b) {
  return (unsigned)f2bf(a) | ((unsigned)f2bf(b) << 16);
}

// ---------------- sort / permute ----------------

__global__ void moe_count(const int* __restrict__ sel, int* __restrict__ meta) {
  __shared__ int se[256];
  __shared__ int cnt[NEXP];
  const int tid = threadIdx.x;
  const int a = blockIdx.x * 256 + tid;
  const int e = sel[a];
  se[tid] = e;
  if (tid < NEXP) cnt[tid] = 0;
  __syncthreads();
  int r = 0;
  for (int j = 0; j < tid; ++j) r += (se[j] == e) ? 1 : 0;
  meta[OFF_LRANK + a] = r;
  atomicAdd(&cnt[e], 1);
  __syncthreads();
  if (tid < NEXP) meta[OFF_COUNTS + blockIdx.x * NEXP + tid] = cnt[tid];
}

__global__ void moe_scan(int* __restrict__ meta) {
  if (threadIdx.x != 0) return;
  int tot[NEXP];
  int base[NEXP + 1];
  for (int e = 0; e < NEXP; ++e) tot[e] = 0;
  for (int c = 0; c < 32; ++c)
    for (int e = 0; e < NEXP; ++e) tot[e] += meta[OFF_COUNTS + c * NEXP + e];
  base[0] = 0;
  for (int e = 0; e < NEXP; ++e) base[e + 1] = base[e] + tot[e];
  int run[NEXP];
  for (int e = 0; e < NEXP; ++e) run[e] = 0;
  for (int c = 0; c < 32; ++c)
    for (int e = 0; e < NEXP; ++e) {
      int v = meta[OFF_COUNTS + c * NEXP + e];
      meta[OFF_COUNTS + c * NEXP + e] = base[e] + run[e];
      run[e] += v;
    }
  for (int e = 0; e <= NEXP; ++e) meta[OFF_ESTART + e] = base[e];
  int nt = 0;
  for (int e = 0; e < NEXP; ++e) {
    for (int i = 0; i * 128 < tot[e]; ++i) {
      meta[OFF_TROW0 + nt] = base[e] + i * 128;
      meta[OFF_TREND + nt] = base[e] + tot[e];
      meta[OFF_TE + nt] = e;
      ++nt;
    }
  }
  for (; nt < MT_MAX; ++nt) {
    meta[OFF_TROW0 + nt] = 0;
    meta[OFF_TREND + nt] = 0;  // row0 >= row_end -> tile inactive
    meta[OFF_TE + nt] = 0;
  }
}

__global__ void moe_scatter(const int* __restrict__ sel, int* __restrict__ meta) {
  const int tid = threadIdx.x;
  const int a = blockIdx.x * 256 + tid;
  const int e = sel[a];
  const int pos = meta[OFF_COUNTS + blockIdx.x * NEXP + e] + meta[OFF_LRANK + a];
  meta[OFF_ROWSRC + pos] = a;
  meta[OFF_POSOF + a] = pos;
}

// ---------------- GEMM1: fused gating+up, SiLU(g)*u -> h (bf16) ----------------
// grid: x = MT_MAX (m-tiles, fast-varying for weight L3 reuse), y = FDIM/64

__global__ __launch_bounds__(256, 2)
void moe_gemm1(const float* __restrict__ x, const float* __restrict__ Wg,
               const float* __restrict__ Wu, const int* __restrict__ meta,
               unsigned short* __restrict__ h) {
  const int mt = blockIdx.x;
  const int row0 = meta[OFF_TROW0 + mt];
  const int row_end = meta[OFF_TREND + mt];
  if (row0 >= row_end) return;
  const int e = meta[OFF_TE + mt];
  const int n0 = blockIdx.y * 64;

  __shared__ __align__(16) unsigned short As[128][40];      // [m][k], +8 pad
  __shared__ __align__(16) unsigned short Bs[2][64][40];    // [mat][n][k] transposed, +8 pad

  const int tid = threadIdx.x;
  // A staging: thread -> (row = tid>>1, k-half = (tid&1)*16)
  const int ar = tid >> 1;
  const int ak = (tid & 1) * 16;
  int rg = row0 + ar; if (rg > ATOT - 1) rg = ATOT - 1;
  const int tokenA = meta[OFF_ROWSRC + rg] >> 1;  // assignment / X
  const float* xrow = x + (size_t)tokenA * DDIM + ak;
  // B staging: mat = tid>>7; within: 8 n x 2 k per thread
  const int bm = tid >> 7;
  const int bu = tid & 127;
  const int bng = (bu & 7) * 8;
  const int bkp = (bu >> 3) * 2;
  const float* wsrc = (bm ? Wu : Wg) + (size_t)e * DDIM * FDIM + n0 + bng;

  // wave decomposition: 4 waves in 2x2, each 64 rows x 32 cols x 2 mats
  const int wid = tid >> 6, lane = tid & 63;
  const int wm = (wid & 1) * 64;
  const int wn = (wid >> 1) * 32;
  const int lr = lane & 15, lg = lane >> 4;

  f32x4 acc[2][4][2];
  #pragma unroll
  for (int q = 0; q < 2; ++q)
    #pragma unroll
    for (int m = 0; m < 4; ++m)
      #pragma unroll
      for (int n = 0; n < 2; ++n)
        #pragma unroll
        for (int j = 0; j < 4; ++j) acc[q][m][n][j] = 0.0f;

  float4 a0, a1, a2, a3, b0, b1, b2, b3;
  a0 = *(const float4*)(xrow + 0);  a1 = *(const float4*)(xrow + 4);
  a2 = *(const float4*)(xrow + 8);  a3 = *(const float4*)(xrow + 12);
  {
    const float* wp = wsrc + (size_t)bkp * FDIM;
    b0 = *(const float4*)(wp);            b1 = *(const float4*)(wp + 4);
    b2 = *(const float4*)(wp + FDIM);     b3 = *(const float4*)(wp + FDIM + 4);
  }

  for (int k0 = 0; k0 < DDIM; k0 += 32) {
    __syncthreads();
    // write A (cvt fp32->bf16)
    uint4 wA0, wA1;
    wA0.x = pack2(a0.x, a0.y); wA0.y = pack2(a0.z, a0.w);
    wA0.z = pack2(a1.x, a1.y); wA0.w = pack2(a1.z, a1.w);
    wA1.x = pack2(a2.x, a2.y); wA1.y = pack2(a2.z, a2.w);
    wA1.z = pack2(a3.x, a3.y); wA1.w = pack2(a3.z, a3.w);
    *(uint4*)&As[ar][ak] = wA0;
    *(uint4*)&As[ar][ak + 8] = wA1;
    // write B transposed: Bs[mat][n][k]
    {
      float lo[8] = {b0.x, b0.y, b0.z, b0.w, b1.x, b1.y, b1.z, b1.w};
      float hi[8] = {b2.x, b2.y, b2.z, b2.w, b3.x, b3.y, b3.z, b3.w};
      #pragma unroll
      for (int j = 0; j < 8; ++j)
        *(unsigned*)&Bs[bm][bng + j][bkp] = pack2(lo[j], hi[j]);
    }
    __syncthreads();
    // prefetch next K-step (overlaps with MFMA below)
    if (k0 + 32 < DDIM) {
      const float* xp = xrow + k0 + 32;
      a0 = *(const float4*)(xp);      a1 = *(const float4*)(xp + 4);
      a2 = *(const float4*)(xp + 8);  a3 = *(const float4*)(xp + 12);
      const float* wp = wsrc + (size_t)(k0 + 32 + bkp) * FDIM;
      b0 = *(const float4*)(wp);        b1 = *(const float4*)(wp + 4);
      b2 = *(const float4*)(wp + FDIM); b3 = *(const float4*)(wp + FDIM + 4);
    }
    // fragments + MFMA
    bf16x8 af[4], bfr[2][2];
    #pragma unroll
    for (int m = 0; m < 4; ++m)
      af[m] = *(const bf16x8*)&As[wm + m * 16 + lr][lg * 8];
    #pragma unroll
    for (int q = 0; q < 2; ++q)
      #pragma unroll
      for (int n = 0; n < 2; ++n)
        bfr[q][n] = *(const bf16x8*)&Bs[q][wn + n * 16 + lr][lg * 8];
    #pragma unroll
    for (int q = 0; q < 2; ++q)
      #pragma unroll
      for (int m = 0; m < 4; ++m)
        #pragma unroll
        for (int n = 0; n < 2; ++n)
          acc[q][m][n] = __builtin_amdgcn_mfma_f32_16x16x32_bf16(
              af[m], bfr[q][n], acc[q][m][n], 0, 0, 0);
  }

  // epilogue: h = silu(g) * u, bf16
  #pragma unroll
  for (int m = 0; m < 4; ++m)
    #pragma unroll
    for (int n = 0; n < 2; ++n)
      #pragma unroll
      for (int j = 0; j < 4; ++j) {
        const int rgl = row0 + wm + m * 16 + lg * 4 + j;
        if (rgl < row_end) {
          const float g = acc[0][m][n][j];
          const float u = acc[1][m][n][j];
          const float hv = (g / (1.0f + __expf(-g))) * u;
          h[(size_t)rgl * FDIM + (n0 + wn + n * 16 + lr)] = f2bf(hv);
        }
      }
}

// ---------------- GEMM2: down = h @ Wd[e] -> fp32 ----------------
// grid: x = MT_MAX, y = DDIM/128

__global__ __launch_bounds__(256, 2)
void moe_gemm2(const unsigned short* __restrict__ h, const float* __restrict__ Wd,
               const int* __restrict__ meta, float* __restrict__ down) {
  const int mt = blockIdx.x;
  const int row0 = meta[OFF_TROW0 + mt];
  const int row_end = meta[OFF_TREND + mt];
  if (row0 >= row_end) return;
  const int e = meta[OFF_TE + mt];
  const int n0 = blockIdx.y * 128;

  __shared__ __align__(16) unsigned short As[128][40];
  __shared__ __align__(16) unsigned short Bs[128][40];

  const int tid = threadIdx.x;
  const int ar = tid >> 1;
  const int ak = (tid & 1) * 16;
  int rg = row0 + ar; if (rg > ATOT - 1) rg = ATOT - 1;
  const unsigned short* hrow = h + (size_t)rg * FDIM + ak;

  const int bng = (tid & 15) * 8;
  const int bkp = (tid >> 4) * 2;
  const float* wsrc = Wd + (size_t)e * FDIM * DDIM + n0 + bng;

  const int wid = tid >> 6, lane = tid & 63;
  const int wm = (wid & 1) * 64, wn = (wid >> 1) * 64;
  const int lr = lane & 15, lg = lane >> 4;

  f32x4 acc[4][4];
  #pragma unroll
  for (int m = 0; m < 4; ++m)
    #pragma unroll
    for (int n = 0; n < 4; ++n)
      #pragma unroll
      for (int j = 0; j < 4; ++j) acc[m][n][j] = 0.0f;

  uint4 va0, va1;
  float4 b0, b1, b2, b3;
  va0 = *(const uint4*)(hrow);
  va1 = *(const uint4*)(hrow + 8);
  {
    const float* wp = wsrc + (size_t)bkp * DDIM;
    b0 = *(const float4*)(wp);        b1 = *(const float4*)(wp + 4);
    b2 = *(const float4*)(wp + DDIM); b3 = *(const float4*)(wp + DDIM + 4);
  }

  for (int k0 = 0; k0 < FDIM; k0 += 32) {
    __syncthreads();
    *(uint4*)&As[ar][ak] = va0;
    *(uint4*)&As[ar][ak + 8] = va1;
    {
      float lo[8] = {b0.x, b0.y, b0.z, b0.w, b1.x, b1.y, b1.z, b1.w};
      float hi[8] = {b2.x, b2.y, b2.z, b2.w, b3.x, b3.y, b3.z, b3.w};
      #pragma unroll
      for (int j = 0; j < 8; ++j)
        *(unsigned*)&Bs[bng + j][bkp] = pack2(lo[j], hi[j]);
    }
    __syncthreads();
    if (k0 + 32 < FDIM) {
      const unsigned short* hp = hrow + k0 + 32;
      va0 = *(const uint4*)(hp);
      va1 = *(const uint4*)(hp + 8);
      const float* wp = wsrc + (size_t)(k0 + 32 + bkp) * DDIM;
      b0 = *(const float4*)(wp);        b1 = *(const float4*)(wp + 4);
      b2 = *(const float4*)(wp + DDIM); b3 = *(const float4*)(wp + DDIM + 4);
    }
    bf16x8 af[4], bfr[4];
    #pragma unroll
    for (int m = 0; m < 4; ++m)
      af[m] = *(const bf16x8*)&As[wm + m * 16 + lr][lg * 8];
    #pragma unroll
    for (int n = 0; n < 4; ++n)
      bfr[n] = *(const bf16x8*)&Bs[wn + n * 16 + lr][lg * 8];
    #pragma unroll
    for (int m = 0; m < 4; ++m)
      #pragma unroll
      for (int n = 0; n < 4; ++n)
        acc[m][n] = __builtin_amdgcn_mfma_f32_16x16x32_bf16(af[m], bfr[n], acc[m][n], 0, 0, 0);
  }

  #pragma unroll
  for (int m = 0; m < 4; ++m)
    #pragma unroll
    for (int n = 0; n < 4; ++n)
      #pragma unroll
      for (int j = 0; j < 4; ++j) {
        const int rgl = row0 + wm + m * 16 + lg * 4 + j;
        if (rgl < row_end)
          down[(size_t)rgl * DDIM + (n0 + wn + n * 16 + lr)] = acc[m][n][j];
      }
}

// ---------------- combine: out[t] = sum_x rw[t,x] * down[pos_of[t*X+x]] ----------------

__global__ void moe_combine(const float* __restrict__ down, const float* __restrict__ rw,
                            const int* __restrict__ meta, float* __restrict__ out) {
  const int t = blockIdx.x;
  const int p0 = meta[OFF_POSOF + 2 * t];
  const int p1 = meta[OFF_POSOF + 2 * t + 1];
  const float w0 = rw[2 * t], w1 = rw[2 * t + 1];
  const float4* d0 = (const float4*)(down + (size_t)p0 * DDIM);
  const float4* d1 = (const float4*)(down + (size_t)p1 * DDIM);
  float4* o = (float4*)(out + (size_t)t * DDIM);
  for (int i = threadIdx.x; i < DDIM / 4; i += 256) {
    const float4 a = d0[i], b = d1[i];
    o[i] = make_float4(w0 * a.x + w1 * b.x, w0 * a.y + w1 * b.y,
                       w0 * a.z + w1 * b.z, w0 * a.w + w1 * b.w);
  }
}

// ---------------- launch ----------------

extern "C" void kernel_launch(void* const* d_in, const int* in_sizes, int n_in,
                              void* d_out, int out_size, void* d_ws, size_t ws_size,
                              hipStream_t stream) {
  const float* x  = (const float*)d_in[0];
  const float* rw = (const float*)d_in[1];
  const int*   sel = (const int*)d_in[2];
  const float* Wg = (const float*)d_in[3];
  const float* Wu = (const float*)d_in[4];
  const float* Wd = (const float*)d_in[5];
  float* out = (float*)d_out;

  // workspace: h (bf16, 64MB) | down (fp32, 64MB) | meta (~100KB)
  unsigned short* h = (unsigned short*)d_ws;
  float* down = (float*)((char*)d_ws + (size_t)ATOT * FDIM * 2);
  int* meta = (int*)((char*)d_ws + (size_t)ATOT * FDIM * 2 + (size_t)ATOT * DDIM * 4);

  moe_count<<<32, 256, 0, stream>>>(sel, meta);
  moe_scan<<<1, 64, 0, stream>>>(meta);
  moe_scatter<<<32, 256, 0, stream>>>(sel, meta);
  moe_gemm1<<<dim3(MT_MAX, FDIM / 64), 256, 0, stream>>>(x, Wg, Wu, meta, h);
  moe_gemm2<<<dim3(MT_MAX, DDIM / 128), 256, 0, stream>>>(h, Wd, meta, down);
  moe_combine<<<T_TOK, 256, 0, stream>>>(down, rw, meta, out);
}